// Round 1
// baseline (183.116 us; speedup 1.0000x reference)
//
#include <hip/hip_runtime.h>

// out[m,n] = prod_d softplus(min(Zm,Ze)-max(zm,ze)) / softplus(Zm-zm)
//
// v2 changes vs v1 (88us/dispatch, 28% occupancy):
//  - D=64 split into two 32-d halves staged alternately: LDS 53.8KB -> 35.9KB
//    -> 4 blocks/CU (16 waves, 50% occupancy) with __launch_bounds__(256,4).
//  - 64x64 block tile, 4x4 per-thread register tile: 4 x ds_read_b128 serve
//    16 units/d (4 B/unit vs 6 B/unit) -> LDS pipe ~25us model vs ~37us.
//    Halved m-block count also halves entity global re-reads.
//  - staging: per-thread 8-consecutive-d float4 global loads (vectorized);
//    LDS write conflicts 4-way (was 8-way).
//
// Math identical to v1 (verified numerics):
//  - product-of-ratios in log2 domain; ln2^64 cancels between numerator and
//    denominator -> inner unit is raw v_log_f32 only.
//  - e^{hi-lo} = min(e^Zm,e^Ze) * min(e^-zm,e^-ze): row exps staged in LDS.
//  - 1/sp_men applied once per 8-d chunk from small LDS array.
//  - no log1p fixup needed: u >= ~1e-4 -> per-dim rel err <= 5e-4 ->
//    output err ~2e-14 << tolerance. Flush bound unchanged.

#define BM 64
#define BN 64
#define DH 32    // d-half staged per pass
#define ST 68    // LDS row stride (mult of 4 -> 16B-aligned float4 rows)
#define CLEN 8
#define NCH 4    // 8-d chunks per half

__global__ __launch_bounds__(256, 4)
void ivr_kernel(const float* __restrict__ men, const float* __restrict__ en,
                float* __restrict__ out, int M, int N) {
    __shared__ __align__(16) float sEm[DH][ST];   // e^{Zm}   [d][m]
    __shared__ __align__(16) float sIm[DH][ST];   // e^{-zm}
    __shared__ __align__(16) float sEe[DH][ST];   // e^{Ze}   [d][n]
    __shared__ __align__(16) float sIe[DH][ST];   // e^{-ze}
    __shared__ __align__(16) float sRc[NCH][ST];  // 1/prod_chunk log2(1+e^{Zm-zm})

    const int tx = threadIdx.x;
    const int m0 = blockIdx.y * BM;
    const int n0 = blockIdx.x * BN;

    const int ni = (tx & 15) * 4;   // 16 n-groups of 4
    const int mi = (tx >> 4) * 4;   // 16 m-groups of 4
    const int sr = tx >> 2;         // staging row 0..63
    const int sc = tx & 3;          // staging sub-chunk 0..3 (8 d each)

    int mm = m0 + sr; if (mm >= M) mm = M - 1;
    int nn = n0 + sr; if (nn >= N) nn = N - 1;
    const float* mrow = men + (size_t)mm * 128 + sc * CLEN;
    const float* erow = en  + (size_t)nn * 128 + sc * CLEN;

    float p[4][4];
    #pragma unroll
    for (int i = 0; i < 4; ++i)
        #pragma unroll
        for (int j = 0; j < 4; ++j) p[i][j] = 1.0f;

    #pragma unroll 1
    for (int h = 0; h < 2; ++h) {
        if (h) __syncthreads();     // prev-half compute done before overwrite

        // ---- men staging: thread -> (row sr, 8 consecutive d) ----
        {
            const float* r = mrow + h * DH;
            const float4 a0 = *reinterpret_cast<const float4*>(r);        // z
            const float4 a1 = *reinterpret_cast<const float4*>(r + 4);
            const float4 b0 = *reinterpret_cast<const float4*>(r + 64);   // Z
            const float4 b1 = *reinterpret_cast<const float4*>(r + 68);
            const float zA[8] = {a0.x,a0.y,a0.z,a0.w,a1.x,a1.y,a1.z,a1.w};
            const float ZA[8] = {b0.x,b0.y,b0.z,b0.w,b1.x,b1.y,b1.z,b1.w};
            float prod = 1.0f;
            #pragma unroll
            for (int k = 0; k < CLEN; ++k) {
                const int dl = sc * CLEN + k;
                const float Em = __expf(ZA[k]);
                const float Im = __expf(-zA[k]);
                sEm[dl][sr] = Em;
                sIm[dl][sr] = Im;
                prod *= __log2f(1.0f + Em * Im);   // log2 softplus (ln2 cancels)
            }
            sRc[sc][sr] = 1.0f / prod;
        }
        // ---- entity staging (same mapping) ----
        {
            const float* r = erow + h * DH;
            const float4 a0 = *reinterpret_cast<const float4*>(r);        // z
            const float4 a1 = *reinterpret_cast<const float4*>(r + 4);
            const float4 b0 = *reinterpret_cast<const float4*>(r + 64);   // Z
            const float4 b1 = *reinterpret_cast<const float4*>(r + 68);
            const float zA[8] = {a0.x,a0.y,a0.z,a0.w,a1.x,a1.y,a1.z,a1.w};
            const float ZA[8] = {b0.x,b0.y,b0.z,b0.w,b1.x,b1.y,b1.z,b1.w};
            #pragma unroll
            for (int k = 0; k < CLEN; ++k) {
                const int dl = sc * CLEN + k;
                sEe[dl][sr] = __expf(ZA[k]);
                sIe[dl][sr] = __expf(-zA[k]);
            }
        }
        __syncthreads();

        // ---- compute: 4 chunks x 8 d, 4x4 units per d ----
        #pragma unroll 1                // keep code size ~1 chunk (I$-friendly)
        for (int c = 0; c < NCH; ++c) {
            #pragma unroll
            for (int k = 0; k < CLEN; ++k) {
                const int d = c * CLEN + k;
                const float4 Em4 = *reinterpret_cast<const float4*>(&sEm[d][mi]);
                const float4 Im4 = *reinterpret_cast<const float4*>(&sIm[d][mi]);
                const float4 Ee4 = *reinterpret_cast<const float4*>(&sEe[d][ni]);
                const float4 Ie4 = *reinterpret_cast<const float4*>(&sIe[d][ni]);
                const float EmA[4] = {Em4.x, Em4.y, Em4.z, Em4.w};
                const float ImA[4] = {Im4.x, Im4.y, Im4.z, Im4.w};
                const float EeA[4] = {Ee4.x, Ee4.y, Ee4.z, Ee4.w};
                const float IeA[4] = {Ie4.x, Ie4.y, Ie4.z, Ie4.w};
                #pragma unroll
                for (int i = 0; i < 4; ++i) {
                    #pragma unroll
                    for (int j = 0; j < 4; ++j) {
                        const float u = fminf(EmA[i], EeA[j]) * fminf(ImA[i], IeA[j]);
                        p[i][j] *= __log2f(1.0f + u);   // raw v_log_f32
                    }
                }
            }
            const float4 rc4 = *reinterpret_cast<const float4*>(&sRc[c][mi]);
            const float rcA[4] = {rc4.x, rc4.y, rc4.z, rc4.w};
            #pragma unroll
            for (int i = 0; i < 4; ++i) {
                #pragma unroll
                for (int j = 0; j < 4; ++j) p[i][j] *= rcA[i];
            }
        }
    }

    // ---- store: 4 rows x float4 per thread ----
    #pragma unroll
    for (int i = 0; i < 4; ++i) {
        const int m = m0 + mi + i;
        if (m >= M) continue;
        const int n = n0 + ni;
        float* o = out + (size_t)m * N + n;
        if (n + 4 <= N) {
            *reinterpret_cast<float4*>(o) = make_float4(p[i][0], p[i][1], p[i][2], p[i][3]);
        } else {
            #pragma unroll
            for (int j = 0; j < 4; ++j)
                if (n + j < N) o[j] = p[i][j];
        }
    }
}

extern "C" void kernel_launch(void* const* d_in, const int* in_sizes, int n_in,
                              void* d_out, int out_size, void* d_ws, size_t ws_size,
                              hipStream_t stream) {
    const float* men = (const float*)d_in[0];
    const float* en  = (const float*)d_in[1];
    float* out = (float*)d_out;
    const int M = in_sizes[0] / 128;   // 256
    const int N = in_sizes[1] / 128;   // 20000
    dim3 grid((N + BN - 1) / BN, (M + BM - 1) / BM);
    ivr_kernel<<<grid, dim3(256), 0, stream>>>(men, en, out, M, N);
}

// Round 2
// 180.953 us; speedup vs baseline: 1.0120x; 1.0120x over previous
//
#include <hip/hip_runtime.h>

// out[m,n] = prod_d softplus(min(Zm,Ze)-max(zm,ze)) / softplus(Zm-zm)
//
// v3 = v2 structure (DH=32 half-staging -> 35.9KB LDS -> 4 blocks/CU;
// 64x64 tile, 4x4/thread) with ALL local arrays eliminated.
// v2 post-mortem: WRITE_SIZE 296MB (output is 20MB) -> ~276MB scratch
// writebacks; VGPR=64 w/ local-mem arrays (zA[8]/ZA[8] staging arrays inside
// the non-unrolled h-loop defeated SROA). v3 scalarizes everything:
// staging uses explicit .x/.y/.z/.w component statements, accumulators are
// 16 named scalars p00..p33, rc-apply and stores are macro-expanded.
//
// Math identical to v1/v2 (verified numerics, absmax 5.6e-17):
//  - product-of-ratios in log2 domain; ln2^64 cancels num/denom -> inner
//    unit is a single raw v_log_f32.
//  - e^{hi-lo} = min(e^Zm,e^Ze) * min(e^-zm,e^-ze): row exps staged in LDS.
//  - 1/sp_men applied once per 8-d chunk.

#define BM 64
#define BN 64
#define DH 32    // d-half staged per pass
#define ST 68    // LDS row stride (mult of 4 -> 16B-aligned float4 rows)
#define NCH 4    // 8-d chunks per half

// staging: one (d, exp-pair) -> LDS + chunk-product update
#define MSTG(K, ZV, ZZ) { const float Em_ = __expf(ZZ); const float Im_ = __expf(-(ZV)); \
    sEm[db + (K)][sr] = Em_; sIm[db + (K)][sr] = Im_; prod *= __log2f(1.0f + Em_ * Im_); }
#define ESTG(K, ZV, ZZ) { sEe[db + (K)][sr] = __expf(ZZ); sIe[db + (K)][sr] = __expf(-(ZV)); }
// one fused-dim unit
#define FD(PIJ, EMc, IMc, EEc, IEc) PIJ *= __log2f(1.0f + fminf(EMc, EEc) * fminf(IMc, IEc));

__global__ __launch_bounds__(256, 4)
void ivr_kernel(const float* __restrict__ men, const float* __restrict__ en,
                float* __restrict__ out, int M, int N) {
    __shared__ __align__(16) float sEm[DH][ST];   // e^{Zm}   [d][m]
    __shared__ __align__(16) float sIm[DH][ST];   // e^{-zm}
    __shared__ __align__(16) float sEe[DH][ST];   // e^{Ze}   [d][n]
    __shared__ __align__(16) float sIe[DH][ST];   // e^{-ze}
    __shared__ __align__(16) float sRc[NCH][ST];  // 1/prod_chunk log2(1+e^{Zm-zm})

    const int tx = threadIdx.x;
    const int m0 = blockIdx.y * BM;
    const int n0 = blockIdx.x * BN;

    const int ni = (tx & 15) * 4;   // 16 n-groups of 4
    const int mi = (tx >> 4) * 4;   // 16 m-groups of 4
    const int sr = tx >> 2;         // staging row 0..63
    const int sc = tx & 3;          // staging sub-chunk 0..3 (8 d each)
    const int db = sc * 8;          // base local-d of this thread's chunk

    int mm = m0 + sr; if (mm >= M) mm = M - 1;
    int nn = n0 + sr; if (nn >= N) nn = N - 1;
    const float* mrow = men + (size_t)mm * 128 + db;
    const float* erow = en  + (size_t)nn * 128 + db;

    float p00=1.f,p01=1.f,p02=1.f,p03=1.f;
    float p10=1.f,p11=1.f,p12=1.f,p13=1.f;
    float p20=1.f,p21=1.f,p22=1.f,p23=1.f;
    float p30=1.f,p31=1.f,p32=1.f,p33=1.f;

    #pragma unroll 1
    for (int h = 0; h < 2; ++h) {
        if (h) __syncthreads();     // prev-half compute done before overwrite

        // ---- men staging: thread -> (row sr, 8 consecutive d), scalarized ----
        {
            const float* r = mrow + h * DH;
            const float4 z0 = *reinterpret_cast<const float4*>(r);        // z
            const float4 z1 = *reinterpret_cast<const float4*>(r + 4);
            const float4 Z0 = *reinterpret_cast<const float4*>(r + 64);   // Z
            const float4 Z1 = *reinterpret_cast<const float4*>(r + 68);
            float prod = 1.0f;
            MSTG(0, z0.x, Z0.x) MSTG(1, z0.y, Z0.y) MSTG(2, z0.z, Z0.z) MSTG(3, z0.w, Z0.w)
            MSTG(4, z1.x, Z1.x) MSTG(5, z1.y, Z1.y) MSTG(6, z1.z, Z1.z) MSTG(7, z1.w, Z1.w)
            sRc[sc][sr] = 1.0f / prod;
        }
        // ---- entity staging, scalarized ----
        {
            const float* r = erow + h * DH;
            const float4 z0 = *reinterpret_cast<const float4*>(r);
            const float4 z1 = *reinterpret_cast<const float4*>(r + 4);
            const float4 Z0 = *reinterpret_cast<const float4*>(r + 64);
            const float4 Z1 = *reinterpret_cast<const float4*>(r + 68);
            ESTG(0, z0.x, Z0.x) ESTG(1, z0.y, Z0.y) ESTG(2, z0.z, Z0.z) ESTG(3, z0.w, Z0.w)
            ESTG(4, z1.x, Z1.x) ESTG(5, z1.y, Z1.y) ESTG(6, z1.z, Z1.z) ESTG(7, z1.w, Z1.w)
        }
        __syncthreads();

        // ---- compute: 4 chunks x 8 d, 4x4 units per d, fully scalarized ----
        #pragma unroll 1                // keep code size ~1 chunk (I$-friendly)
        for (int c = 0; c < NCH; ++c) {
            #pragma unroll
            for (int k = 0; k < 8; ++k) {
                const int d = c * 8 + k;
                const float4 Em4 = *reinterpret_cast<const float4*>(&sEm[d][mi]);
                const float4 Im4 = *reinterpret_cast<const float4*>(&sIm[d][mi]);
                const float4 Ee4 = *reinterpret_cast<const float4*>(&sEe[d][ni]);
                const float4 Ie4 = *reinterpret_cast<const float4*>(&sIe[d][ni]);
                FD(p00, Em4.x, Im4.x, Ee4.x, Ie4.x) FD(p01, Em4.x, Im4.x, Ee4.y, Ie4.y)
                FD(p02, Em4.x, Im4.x, Ee4.z, Ie4.z) FD(p03, Em4.x, Im4.x, Ee4.w, Ie4.w)
                FD(p10, Em4.y, Im4.y, Ee4.x, Ie4.x) FD(p11, Em4.y, Im4.y, Ee4.y, Ie4.y)
                FD(p12, Em4.y, Im4.y, Ee4.z, Ie4.z) FD(p13, Em4.y, Im4.y, Ee4.w, Ie4.w)
                FD(p20, Em4.z, Im4.z, Ee4.x, Ie4.x) FD(p21, Em4.z, Im4.z, Ee4.y, Ie4.y)
                FD(p22, Em4.z, Im4.z, Ee4.z, Ie4.z) FD(p23, Em4.z, Im4.z, Ee4.w, Ie4.w)
                FD(p30, Em4.w, Im4.w, Ee4.x, Ie4.x) FD(p31, Em4.w, Im4.w, Ee4.y, Ie4.y)
                FD(p32, Em4.w, Im4.w, Ee4.z, Ie4.z) FD(p33, Em4.w, Im4.w, Ee4.w, Ie4.w)
            }
            const float4 rc4 = *reinterpret_cast<const float4*>(&sRc[c][mi]);
            p00 *= rc4.x; p01 *= rc4.x; p02 *= rc4.x; p03 *= rc4.x;
            p10 *= rc4.y; p11 *= rc4.y; p12 *= rc4.y; p13 *= rc4.y;
            p20 *= rc4.z; p21 *= rc4.z; p22 *= rc4.z; p23 *= rc4.z;
            p30 *= rc4.w; p31 *= rc4.w; p32 *= rc4.w; p33 *= rc4.w;
        }
    }

    // ---- store: 4 rows x float4 per thread, scalarized ----
    const int n = n0 + ni;
#define STROW(I, A, B, C, D) { const int m_ = m0 + mi + (I); if (m_ < M) { \
    float* o = out + (size_t)m_ * N + n; \
    if (n + 4 <= N) { *reinterpret_cast<float4*>(o) = make_float4(A, B, C, D); } \
    else { if (n < N) o[0] = A; if (n + 1 < N) o[1] = B; if (n + 2 < N) o[2] = C; if (n + 3 < N) o[3] = D; } } }
    STROW(0, p00, p01, p02, p03)
    STROW(1, p10, p11, p12, p13)
    STROW(2, p20, p21, p22, p23)
    STROW(3, p30, p31, p32, p33)
}

extern "C" void kernel_launch(void* const* d_in, const int* in_sizes, int n_in,
                              void* d_out, int out_size, void* d_ws, size_t ws_size,
                              hipStream_t stream) {
    const float* men = (const float*)d_in[0];
    const float* en  = (const float*)d_in[1];
    float* out = (float*)d_out;
    const int M = in_sizes[0] / 128;   // 256
    const int N = in_sizes[1] / 128;   // 20000
    dim3 grid((N + BN - 1) / BN, (M + BM - 1) / BM);
    ivr_kernel<<<grid, dim3(256), 0, stream>>>(men, en, out, M, N);
}

// Round 3
// 176.404 us; speedup vs baseline: 1.0380x; 1.0258x over previous
//
#include <hip/hip_runtime.h>

// out[m,n] = prod_d softplus(min(Zm,Ze)-max(zm,ze)) / softplus(Zm-zm)
//
// v4 = v1 (known-good 88us/dispatch, clean WRITE_SIZE=output) with ONE
// isolated change: D=64 staged in two 32-d halves -> LDS 53.8KB -> 27.2KB
// -> 5 blocks/CU (20 waves, 62.5% occupancy vs 28%). Tile (BM=32, BN=64,
// 2x4/thread), LDS layout/strides, compute body, and stores are v1 VERBATIM.
// v2/v3 post-mortem: their combined restructure (64x64 tile, 4x4 acc,
// new staging) produced ~276MB of unexplained HBM writes (output is 20MB)
// and regressed to 126us; two mispredictions -> retreat and isolate.
//
// Math identical throughout (verified, absmax 5.6e-17):
//  - product-of-ratios in log2 domain; ln2^64 cancels num/denom -> inner
//    unit is a single raw v_log_f32.
//  - e^{hi-lo} = min(e^Zm,e^Ze) * min(e^-zm,e^-ze): row exps staged in LDS.
//  - 1/sp_men applied once per 8-d chunk; complete-chunk prefix products
//    stay in [out, 1] (per-d factor log2(1+u)/log2(1+e^{Zm-zm}) <= 1).

#define BM 32
#define BN 64
#define DD 64
#define DH 32    // d-half staged per pass
#define MST 34   // even (8B-align float2), bank stride 2 -> free 2-way
#define NST 68   // mult of 4 (16B-align float4)
#define CLEN 8
#define NCHUNK 8 // 8-d chunks over the full D (4 per half)

__global__ __launch_bounds__(256, 5)
void ivr_kernel(const float* __restrict__ men, const float* __restrict__ en,
                float* __restrict__ out, int M, int N) {
    __shared__ __align__(16) float sEm[DH][MST];  // e^{Zm}   [dl][m]
    __shared__ __align__(16) float sIm[DH][MST];  // e^{-zm}
    __shared__ __align__(16) float sEe[DH][NST];  // e^{Ze}   [dl][n]
    __shared__ __align__(16) float sIe[DH][NST];  // e^{-ze}
    __shared__ float sRc[NCHUNK][MST];            // 1/prod_{d in chunk} log2(1+e^{Zm-zm})

    const int tx = threadIdx.x;
    const int m0 = blockIdx.y * BM;
    const int n0 = blockIdx.x * BN;

    // men staging mapping (v1): thread -> (m = tx>>3, chunk c8 = tx&7 of 8 d's)
    const int sm = tx >> 3;        // 0..31
    const int c8 = tx & 7;         // 0..7 (global 8-d chunk id)
    int mm = m0 + sm; if (mm >= M) mm = M - 1;
    const float* mrow = men + (size_t)mm * 128;

    const int ni = (tx & 15) * 4;  // 16 n-groups of 4
    const int mi = (tx >> 4) * 2;  // 16 m-groups of 2

    float p[2][4];
    #pragma unroll
    for (int i = 0; i < 2; ++i)
        #pragma unroll
        for (int j = 0; j < 4; ++j) p[i][j] = 1.0f;

    #pragma unroll 1
    for (int h = 0; h < 2; ++h) {
        if (h) __syncthreads();    // prev-half compute done before overwrite

        // ---- men staging: only threads whose chunk lies in this half ----
        if ((c8 >> 2) == h) {
            float prod = 1.0f;
            #pragma unroll
            for (int k = 0; k < CLEN; ++k) {
                const int d  = c8 * CLEN + k;     // global d
                const int dl = d & (DH - 1);      // local d within half
                const float Em = __expf(mrow[DD + d]);
                const float Im = __expf(-mrow[d]);
                sEm[dl][sm] = Em;
                sIm[dl][sm] = Im;
                prod *= __log2f(1.0f + Em * Im);  // log2 softplus (ln2 cancels)
            }
            sRc[c8][sm] = 1.0f / prod;
        }
        // ---- entity staging (coalesced global reads), this half only ----
        for (int i = tx; i < BN * DH; i += 256) {
            const int dl = i & (DH - 1);
            const int n = i >> 5;
            int nn = n0 + n; if (nn >= N) nn = N - 1;
            const int d = h * DH + dl;            // global d
            sEe[dl][n] = __expf(en[(size_t)nn * 128 + DD + d]);
            sIe[dl][n] = __expf(-en[(size_t)nn * 128 + d]);
        }
        __syncthreads();

        // ---- compute: 4 chunks x 8 d this half, 2x4 units per d (v1 body) ----
        #pragma unroll 1               // keep code size ~1 chunk (I$-friendly)
        for (int c = 0; c < NCHUNK / 2; ++c) {
            #pragma unroll
            for (int k = 0; k < CLEN; ++k) {
                const int dl = c * CLEN + k;
                const float2 Em2 = *reinterpret_cast<const float2*>(&sEm[dl][mi]);
                const float2 Im2 = *reinterpret_cast<const float2*>(&sIm[dl][mi]);
                const float4 Ee4 = *reinterpret_cast<const float4*>(&sEe[dl][ni]);
                const float4 Ie4 = *reinterpret_cast<const float4*>(&sIe[dl][ni]);
                const float EmA[2] = {Em2.x, Em2.y};
                const float ImA[2] = {Im2.x, Im2.y};
                const float EeA[4] = {Ee4.x, Ee4.y, Ee4.z, Ee4.w};
                const float IeA[4] = {Ie4.x, Ie4.y, Ie4.z, Ie4.w};
                #pragma unroll
                for (int i = 0; i < 2; ++i) {
                    #pragma unroll
                    for (int j = 0; j < 4; ++j) {
                        const float u = fminf(EmA[i], EeA[j]) * fminf(ImA[i], IeA[j]);
                        p[i][j] *= __log2f(1.0f + u);   // raw v_log_f32
                    }
                }
            }
            const int cg = h * (NCHUNK / 2) + c;  // global chunk id
            const float rc0 = sRc[cg][mi];
            const float rc1 = sRc[cg][mi + 1];
            #pragma unroll
            for (int j = 0; j < 4; ++j) { p[0][j] *= rc0; p[1][j] *= rc1; }
        }
    }

    // ---- store (v1 verbatim) ----
    #pragma unroll
    for (int i = 0; i < 2; ++i) {
        const int m = m0 + mi + i;
        if (m >= M) continue;
        const int n = n0 + ni;
        if (n + 4 <= N) {
            *reinterpret_cast<float4*>(&out[(size_t)m * N + n]) =
                make_float4(p[i][0], p[i][1], p[i][2], p[i][3]);
        } else {
            #pragma unroll
            for (int j = 0; j < 4; ++j)
                if (n + j < N) out[(size_t)m * N + n + j] = p[i][j];
        }
    }
}

extern "C" void kernel_launch(void* const* d_in, const int* in_sizes, int n_in,
                              void* d_out, int out_size, void* d_ws, size_t ws_size,
                              hipStream_t stream) {
    const float* men = (const float*)d_in[0];
    const float* en  = (const float*)d_in[1];
    float* out = (float*)d_out;
    const int M = in_sizes[0] / 128;   // 256
    const int N = in_sizes[1] / 128;   // 20000
    dim3 grid((N + BN - 1) / BN, (M + BM - 1) / BM);
    ivr_kernel<<<grid, dim3(256), 0, stream>>>(men, en, out, M, N);
}

// Round 4
// 135.956 us; speedup vs baseline: 1.3469x; 1.2975x over previous
//
#include <hip/hip_runtime.h>

// out[m,n] = prod_d softplus(min(Zm,Ze)-max(zm,ze)) / softplus(Zm-zm)
//
// v5 = v1's clean single-phase shape (stage -> 1 barrier -> compute -> store;
// NO outer h-loop) scaled to a 512-thread block for occupancy:
//  - BM=32, BN=128, 2x4 tile/thread. LDS = 16KB men(float2 interleaved)
//    + 64KB entity = 81920 B -> exactly 2 blocks/CU = 16 waves (50% vs 28%).
//  - men (Em,Im) interleaved as float2 -> one ds_read_b128/d (broadcast),
//    entity kept as separate float arrays (float4 reads, 16B lane stride =
//    free 2-way). No padding; staging-write conflicts eaten (once/block).
//  - per-chunk sRc ELIMINATED: row denominator computed in registers at
//    staging (4-d partial/thread, shfl_xor x{1,2,4,8} mul-reduce across the
//    16 lanes of the row), compute thread gets its pair via shfl_xor(.,16).
//    Un-normalized 64-d prefix products: for pairs dominating absmax
//    (out~4e-11, den~2^-10+-8) prefix >= ~2^-60 (safe); underflowing pairs
//    have true out < 1e-20 << 8e-13 tolerance.
// v2/v3/v4 post-mortem: all h-loop variants produced 100-280MB of scratch
// round-trip HBM traffic (WRITE_SIZE >> 20MB output). v5 avoids that
// structure entirely; WRITE_SIZE ~ 20000 KB is the falsifier.
//
// Math per unit (identical numerics path to v1, absmax was 5.6e-17):
//   u = min(Em,Ee)*min(Im,Ie) = e^{min(Zm,Ze)-max(zm,ze)};
//   p *= log2(1+u)  (ln2^64 cancels between numerator and denominator).

#define BM 32
#define BN 128
#define DD 64

// one fused-dim unit
#define FD(PIJ, EMc, IMc, EEc, IEc) PIJ *= __log2f(1.0f + fminf(EMc, EEc) * fminf(IMc, IEc));

__global__ __launch_bounds__(512, 4)
void ivr_kernel(const float* __restrict__ men, const float* __restrict__ en,
                float* __restrict__ out, int M, int N) {
    __shared__ __align__(16) float2 sMen[DD][BM];  // (e^{Zm}, e^{-zm}) [d][m]  16 KB
    __shared__ __align__(16) float  sEe[DD][BN];   // e^{Ze}   [d][n]           32 KB
    __shared__ __align__(16) float  sIe[DD][BN];   // e^{-ze}                   32 KB

    const int tx = threadIdx.x;
    const int m0 = blockIdx.y * BM;
    const int n0 = blockIdx.x * BN;

    // ---- men staging + in-register row denominator ----
    float rden;
    {
        const int ml = tx >> 4;          // row 0..31 (16 threads/row)
        const int dc = (tx & 15) * 4;    // this thread's 4 d's
        int mm = m0 + ml; if (mm >= M) mm = M - 1;
        const float* r = men + (size_t)mm * 128 + dc;
        const float4 z = *reinterpret_cast<const float4*>(r);        // z (min)
        const float4 Z = *reinterpret_cast<const float4*>(r + 64);   // Z (max)
        float Em, Im, prod;
        Em = __expf(Z.x); Im = __expf(-z.x); sMen[dc + 0][ml] = make_float2(Em, Im); prod  = __log2f(1.0f + Em * Im);
        Em = __expf(Z.y); Im = __expf(-z.y); sMen[dc + 1][ml] = make_float2(Em, Im); prod *= __log2f(1.0f + Em * Im);
        Em = __expf(Z.z); Im = __expf(-z.z); sMen[dc + 2][ml] = make_float2(Em, Im); prod *= __log2f(1.0f + Em * Im);
        Em = __expf(Z.w); Im = __expf(-z.w); sMen[dc + 3][ml] = make_float2(Em, Im); prod *= __log2f(1.0f + Em * Im);
        // multiply-reduce the 16 per-thread partials of this row (lanes are a
        // 16-aligned group within one wave)
        prod *= __shfl_xor(prod, 1);
        prod *= __shfl_xor(prod, 2);
        prod *= __shfl_xor(prod, 4);
        prod *= __shfl_xor(prod, 8);
        rden = 1.0f / prod;              // full-row 1/denominator
    }
    // ---- entity staging: thread -> (row nl, 16 d's), scalarized ----
    {
        const int nl = tx >> 2;          // row 0..127 (4 threads/row)
        const int c4 = tx & 3;           // 16-d chunk within the row
        int nn = n0 + nl; if (nn >= N) nn = N - 1;
        const float* r = en + (size_t)nn * 128 + c4 * 16;
#define ESTG4(I) { \
        const float4 z_ = *reinterpret_cast<const float4*>(r + (I) * 4); \
        const float4 Z_ = *reinterpret_cast<const float4*>(r + 64 + (I) * 4); \
        const int d_ = c4 * 16 + (I) * 4; \
        sEe[d_ + 0][nl] = __expf(Z_.x); sIe[d_ + 0][nl] = __expf(-z_.x); \
        sEe[d_ + 1][nl] = __expf(Z_.y); sIe[d_ + 1][nl] = __expf(-z_.y); \
        sEe[d_ + 2][nl] = __expf(Z_.z); sIe[d_ + 2][nl] = __expf(-z_.z); \
        sEe[d_ + 3][nl] = __expf(Z_.w); sIe[d_ + 3][nl] = __expf(-z_.w); }
        ESTG4(0) ESTG4(1) ESTG4(2) ESTG4(3)
#undef ESTG4
    }
    __syncthreads();

    const int ni = (tx & 31) * 4;        // 32 n-groups of 4
    const int mi = (tx >> 5) * 2;        // 16 m-pairs

    // fetch the pair of row-denominators for (mi, mi+1): this thread staged
    // row (tx>>4) = mi + hib; partner lane tx^16 staged the other one.
    const float oden = __shfl_xor(rden, 16);
    const int hib = (tx >> 4) & 1;
    const float rd0 = hib ? oden : rden;
    const float rd1 = hib ? rden : oden;

    float p[2][4];
    #pragma unroll
    for (int i = 0; i < 2; ++i)
        #pragma unroll
        for (int j = 0; j < 4; ++j) p[i][j] = 1.0f;

    #pragma unroll 1                     // keep code size ~1 chunk (I$-friendly)
    for (int c = 0; c < 8; ++c) {
        #pragma unroll
        for (int k = 0; k < 8; ++k) {
            const int d = c * 8 + k;
            const float4 mf  = *reinterpret_cast<const float4*>(&sMen[d][mi]);  // Em0,Im0,Em1,Im1
            const float4 Ee4 = *reinterpret_cast<const float4*>(&sEe[d][ni]);
            const float4 Ie4 = *reinterpret_cast<const float4*>(&sIe[d][ni]);
            FD(p[0][0], mf.x, mf.y, Ee4.x, Ie4.x)
            FD(p[0][1], mf.x, mf.y, Ee4.y, Ie4.y)
            FD(p[0][2], mf.x, mf.y, Ee4.z, Ie4.z)
            FD(p[0][3], mf.x, mf.y, Ee4.w, Ie4.w)
            FD(p[1][0], mf.z, mf.w, Ee4.x, Ie4.x)
            FD(p[1][1], mf.z, mf.w, Ee4.y, Ie4.y)
            FD(p[1][2], mf.z, mf.w, Ee4.z, Ie4.z)
            FD(p[1][3], mf.z, mf.w, Ee4.w, Ie4.w)
        }
    }

    #pragma unroll
    for (int j = 0; j < 4; ++j) { p[0][j] *= rd0; p[1][j] *= rd1; }

    // ---- store: 2 rows x float4 per thread (v1 pattern) ----
    #pragma unroll
    for (int i = 0; i < 2; ++i) {
        const int m = m0 + mi + i;
        if (m >= M) continue;
        const int n = n0 + ni;
        if (n + 4 <= N) {
            *reinterpret_cast<float4*>(&out[(size_t)m * N + n]) =
                make_float4(p[i][0], p[i][1], p[i][2], p[i][3]);
        } else {
            #pragma unroll
            for (int j = 0; j < 4; ++j)
                if (n + j < N) out[(size_t)m * N + n + j] = p[i][j];
        }
    }
}

extern "C" void kernel_launch(void* const* d_in, const int* in_sizes, int n_in,
                              void* d_out, int out_size, void* d_ws, size_t ws_size,
                              hipStream_t stream) {
    const float* men = (const float*)d_in[0];
    const float* en  = (const float*)d_in[1];
    float* out = (float*)d_out;
    const int M = in_sizes[0] / 128;   // 256
    const int N = in_sizes[1] / 128;   // 20000
    dim3 grid((N + BN - 1) / BN, (M + BM - 1) / BM);
    ivr_kernel<<<grid, dim3(512), 0, stream>>>(men, en, out, M, N);
}

// Round 5
// 133.070 us; speedup vs baseline: 1.3761x; 1.0217x over previous
//
#include <hip/hip_runtime.h>

// out[m,n] = prod_d softplus(min(Zm,Ze)-max(zm,ze)) / softplus(Zm-zm)
//
// v6 = v5's clean single-phase shape (stage -> 1 barrier -> compute -> store,
// NO outer loop carrying state) with ONE structural change: block tile
// 32x128 -> 64x64 so LDS = 64KB (was 81920B = exact 2x160KB knife-edge that
// measured only 33% occupancy). 64KB x2 = 128KB <= 160KB -> 2 blocks/CU
// (16 waves, 50%) with 32KB slack. Per-thread tile (2x4), FD math, rden
// in-register scheme unchanged from v5 (80.7us, WRITE_SIZE clean).
// Bundled micro-fixes: entity LDS staging writes now lane->row (bank=lane,
// conflict-free; was 4-way), 1+u via explicit fmaf.
//
// Math per unit (identical numerics to v1..v5, absmax 5.6e-17):
//   u = min(Em,Ee)*min(Im,Ie) = e^{min(Zm,Ze)-max(zm,ze)};
//   p *= log2(1+u); ln2^64 cancels between numerator and denominator;
//   final scale by full-row 1/prod_d log2(1+e^{Zm-zm}) (register-resident,
//   shfl-reduced at staging).

#define BM 64
#define BN 64
#define DD 64

// one fused-dim unit: p *= log2(1 + minE*minI)   (fmaf folds mul+add)
#define FD(PIJ, EMc, IMc, EEc, IEc) \
    PIJ *= __log2f(__builtin_fmaf(fminf(EMc, EEc), fminf(IMc, IEc), 1.0f));

__global__ __launch_bounds__(512, 4)
void ivr_kernel(const float* __restrict__ men, const float* __restrict__ en,
                float* __restrict__ out, int M, int N) {
    __shared__ __align__(16) float2 sMen[DD][BM];  // (e^{Zm}, e^{-zm}) [d][m] 32 KB
    __shared__ __align__(16) float  sEe[DD][BN];   // e^{Ze}   [d][n]          16 KB
    __shared__ __align__(16) float  sIe[DD][BN];   // e^{-ze}                  16 KB

    const int tx = threadIdx.x;
    const int m0 = blockIdx.y * BM;
    const int n0 = blockIdx.x * BN;

    // ---- men staging + in-register row denominator ----
    // thread -> (row ml = tx>>3, 8-d chunk dcM = (tx&7)*8); 8 threads/row
    float rden;
    {
        const int ml  = tx >> 3;         // 0..63
        const int dcM = (tx & 7) * 8;    // this thread's 8 d's
        int mm = m0 + ml; if (mm >= M) mm = M - 1;
        const float* r = men + (size_t)mm * 128 + dcM;
        const float4 z0 = *reinterpret_cast<const float4*>(r);        // z (min)
        const float4 z1 = *reinterpret_cast<const float4*>(r + 4);
        const float4 Z0 = *reinterpret_cast<const float4*>(r + 64);   // Z (max)
        const float4 Z1 = *reinterpret_cast<const float4*>(r + 68);
        float Em, Im, prod;
#define MSTG(K, ZV, ZZ) { Em = __expf(ZZ); Im = __expf(-(ZV)); \
        sMen[dcM + (K)][ml] = make_float2(Em, Im); \
        prod *= __log2f(__builtin_fmaf(Em, Im, 1.0f)); }
        Em = __expf(Z0.x); Im = __expf(-z0.x);
        sMen[dcM + 0][ml] = make_float2(Em, Im);
        prod = __log2f(__builtin_fmaf(Em, Im, 1.0f));
        MSTG(1, z0.y, Z0.y) MSTG(2, z0.z, Z0.z) MSTG(3, z0.w, Z0.w)
        MSTG(4, z1.x, Z1.x) MSTG(5, z1.y, Z1.y) MSTG(6, z1.z, Z1.z) MSTG(7, z1.w, Z1.w)
#undef MSTG
        // multiply-reduce the 8 per-thread partials of this row (8-aligned
        // lane group within one wave)
        prod *= __shfl_xor(prod, 1);
        prod *= __shfl_xor(prod, 2);
        prod *= __shfl_xor(prod, 4);
        rden = 1.0f / prod;              // full-row 1/denominator
    }
    // ---- entity staging: lane -> row (conflict-free LDS writes) ----
    // thread -> (row nl = tx&63, 8-d chunk dcE = (tx>>6)*8, wave-uniform)
    {
        const int nl  = tx & 63;
        const int dcE = (tx >> 6) * 8;
        int nn = n0 + nl; if (nn >= N) nn = N - 1;
        const float* r = en + (size_t)nn * 128 + dcE;
        const float4 z0 = *reinterpret_cast<const float4*>(r);
        const float4 z1 = *reinterpret_cast<const float4*>(r + 4);
        const float4 Z0 = *reinterpret_cast<const float4*>(r + 64);
        const float4 Z1 = *reinterpret_cast<const float4*>(r + 68);
#define ESTG(K, ZV, ZZ) { sEe[dcE + (K)][nl] = __expf(ZZ); \
                          sIe[dcE + (K)][nl] = __expf(-(ZV)); }
        ESTG(0, z0.x, Z0.x) ESTG(1, z0.y, Z0.y) ESTG(2, z0.z, Z0.z) ESTG(3, z0.w, Z0.w)
        ESTG(4, z1.x, Z1.x) ESTG(5, z1.y, Z1.y) ESTG(6, z1.z, Z1.z) ESTG(7, z1.w, Z1.w)
#undef ESTG
    }
    __syncthreads();

    const int ni = (tx & 15) * 4;        // 16 n-groups of 4
    const int mi = (tx >> 4) * 2;        // 32 m-pairs

    // row-denominator pair for (mi, mi+1): this thread staged row ml=tx>>3
    // = mi + hib; partner lane tx^8 staged the sibling row.
    const float oden = __shfl_xor(rden, 8);
    const int hib = (tx >> 3) & 1;
    const float rd0 = hib ? oden : rden;
    const float rd1 = hib ? rden : oden;

    float p[2][4];
    #pragma unroll
    for (int i = 0; i < 2; ++i)
        #pragma unroll
        for (int j = 0; j < 4; ++j) p[i][j] = 1.0f;

    #pragma unroll 1                     // keep code size ~1 chunk (I$-friendly)
    for (int c = 0; c < 8; ++c) {
        #pragma unroll
        for (int k = 0; k < 8; ++k) {
            const int d = c * 8 + k;
            const float4 mf  = *reinterpret_cast<const float4*>(&sMen[d][mi]);  // Em0,Im0,Em1,Im1
            const float4 Ee4 = *reinterpret_cast<const float4*>(&sEe[d][ni]);
            const float4 Ie4 = *reinterpret_cast<const float4*>(&sIe[d][ni]);
            FD(p[0][0], mf.x, mf.y, Ee4.x, Ie4.x)
            FD(p[0][1], mf.x, mf.y, Ee4.y, Ie4.y)
            FD(p[0][2], mf.x, mf.y, Ee4.z, Ie4.z)
            FD(p[0][3], mf.x, mf.y, Ee4.w, Ie4.w)
            FD(p[1][0], mf.z, mf.w, Ee4.x, Ie4.x)
            FD(p[1][1], mf.z, mf.w, Ee4.y, Ie4.y)
            FD(p[1][2], mf.z, mf.w, Ee4.z, Ie4.z)
            FD(p[1][3], mf.z, mf.w, Ee4.w, Ie4.w)
        }
    }

    #pragma unroll
    for (int j = 0; j < 4; ++j) { p[0][j] *= rd0; p[1][j] *= rd1; }

    // ---- store: 2 rows x float4 per thread ----
    #pragma unroll
    for (int i = 0; i < 2; ++i) {
        const int m = m0 + mi + i;
        if (m >= M) continue;
        const int n = n0 + ni;
        if (n + 4 <= N) {
            *reinterpret_cast<float4*>(&out[(size_t)m * N + n]) =
                make_float4(p[i][0], p[i][1], p[i][2], p[i][3]);
        } else {
            #pragma unroll
            for (int j = 0; j < 4; ++j)
                if (n + j < N) out[(size_t)m * N + n + j] = p[i][j];
        }
    }
}

extern "C" void kernel_launch(void* const* d_in, const int* in_sizes, int n_in,
                              void* d_out, int out_size, void* d_ws, size_t ws_size,
                              hipStream_t stream) {
    const float* men = (const float*)d_in[0];
    const float* en  = (const float*)d_in[1];
    float* out = (float*)d_out;
    const int M = in_sizes[0] / 128;   // 256
    const int N = in_sizes[1] / 128;   // 20000
    dim3 grid((N + BN - 1) / BN, (M + BM - 1) / BM);
    ivr_kernel<<<grid, dim3(512), 0, stream>>>(men, en, out, M, N);
}

// Round 6
// 133.059 us; speedup vs baseline: 1.3762x; 1.0001x over previous
//
#include <hip/hip_runtime.h>

// out[m,n] = prod_d softplus(min(Zm,Ze)-max(zm,ze)) / softplus(Zm-zm)
//
// v7 = v6 byte-identical EXCEPT: __log2f -> __builtin_amdgcn_logf (raw
// v_log_f32, base-2) in the FD macro + both staging softplus sites.
// v6 post-mortem: VALUBusy*dur is INVARIANT ~63-66us across v1/v5/v6 ->
// VALU-pipe execution-bound; ~30 cy per fused-dim unit vs ~16 visible ->
// ~14 cy/unit hidden cost. Suspect: llvm.log2.f32 lowering carries a
// denormal-input guard (v_cmp+cndmask+ldexp+fixup, ~4-5 full-rate ops)
// around v_log_f32. Our log args are 1+u >= 1.0 (never denormal), so the
// raw builtin is exact-identical numerically and drops the guard.
// Falsifier: if VALUBusy*dur doesn't fall, __log2f was already raw.
//
// Structure (v6): single-phase stage -> 1 barrier -> compute -> store;
// BM=64 BN=64, 512 threads, 2x4/thread; LDS 64KB (2 blocks/CU);
// men (e^Zm,e^-zm) interleaved float2 [d][m]; entity split arrays [d][n];
// lane->row conflict-free entity staging; row denominator in registers
// (shfl_xor mul-reduce at staging).
//
// Math per unit (identical numerics to v1..v6, absmax 5.6e-17):
//   u = min(Em,Ee)*min(Im,Ie) = e^{min(Zm,Ze)-max(zm,ze)};
//   p *= log2(1+u); ln2^64 cancels between numerator and denominator;
//   final scale by full-row 1/prod_d log2(1+e^{Zm-zm}).

#define BM 64
#define BN 64
#define DD 64

// one fused-dim unit: p *= log2(1 + minE*minI)  -- raw v_log_f32
#define FD(PIJ, EMc, IMc, EEc, IEc) \
    PIJ *= __builtin_amdgcn_logf(__builtin_fmaf(fminf(EMc, EEc), fminf(IMc, IEc), 1.0f));

__global__ __launch_bounds__(512, 4)
void ivr_kernel(const float* __restrict__ men, const float* __restrict__ en,
                float* __restrict__ out, int M, int N) {
    __shared__ __align__(16) float2 sMen[DD][BM];  // (e^{Zm}, e^{-zm}) [d][m] 32 KB
    __shared__ __align__(16) float  sEe[DD][BN];   // e^{Ze}   [d][n]          16 KB
    __shared__ __align__(16) float  sIe[DD][BN];   // e^{-ze}                  16 KB

    const int tx = threadIdx.x;
    const int m0 = blockIdx.y * BM;
    const int n0 = blockIdx.x * BN;

    // ---- men staging + in-register row denominator ----
    // thread -> (row ml = tx>>3, 8-d chunk dcM = (tx&7)*8); 8 threads/row
    float rden;
    {
        const int ml  = tx >> 3;         // 0..63
        const int dcM = (tx & 7) * 8;    // this thread's 8 d's
        int mm = m0 + ml; if (mm >= M) mm = M - 1;
        const float* r = men + (size_t)mm * 128 + dcM;
        const float4 z0 = *reinterpret_cast<const float4*>(r);        // z (min)
        const float4 z1 = *reinterpret_cast<const float4*>(r + 4);
        const float4 Z0 = *reinterpret_cast<const float4*>(r + 64);   // Z (max)
        const float4 Z1 = *reinterpret_cast<const float4*>(r + 68);
        float Em, Im, prod;
#define MSTG(K, ZV, ZZ) { Em = __expf(ZZ); Im = __expf(-(ZV)); \
        sMen[dcM + (K)][ml] = make_float2(Em, Im); \
        prod *= __builtin_amdgcn_logf(__builtin_fmaf(Em, Im, 1.0f)); }
        Em = __expf(Z0.x); Im = __expf(-z0.x);
        sMen[dcM + 0][ml] = make_float2(Em, Im);
        prod = __builtin_amdgcn_logf(__builtin_fmaf(Em, Im, 1.0f));
        MSTG(1, z0.y, Z0.y) MSTG(2, z0.z, Z0.z) MSTG(3, z0.w, Z0.w)
        MSTG(4, z1.x, Z1.x) MSTG(5, z1.y, Z1.y) MSTG(6, z1.z, Z1.z) MSTG(7, z1.w, Z1.w)
#undef MSTG
        // multiply-reduce the 8 per-thread partials of this row (8-aligned
        // lane group within one wave)
        prod *= __shfl_xor(prod, 1);
        prod *= __shfl_xor(prod, 2);
        prod *= __shfl_xor(prod, 4);
        rden = 1.0f / prod;              // full-row 1/denominator
    }
    // ---- entity staging: lane -> row (conflict-free LDS writes) ----
    // thread -> (row nl = tx&63, 8-d chunk dcE = (tx>>6)*8, wave-uniform)
    {
        const int nl  = tx & 63;
        const int dcE = (tx >> 6) * 8;
        int nn = n0 + nl; if (nn >= N) nn = N - 1;
        const float* r = en + (size_t)nn * 128 + dcE;
        const float4 z0 = *reinterpret_cast<const float4*>(r);
        const float4 z1 = *reinterpret_cast<const float4*>(r + 4);
        const float4 Z0 = *reinterpret_cast<const float4*>(r + 64);
        const float4 Z1 = *reinterpret_cast<const float4*>(r + 68);
#define ESTG(K, ZV, ZZ) { sEe[dcE + (K)][nl] = __expf(ZZ); \
                          sIe[dcE + (K)][nl] = __expf(-(ZV)); }
        ESTG(0, z0.x, Z0.x) ESTG(1, z0.y, Z0.y) ESTG(2, z0.z, Z0.z) ESTG(3, z0.w, Z0.w)
        ESTG(4, z1.x, Z1.x) ESTG(5, z1.y, Z1.y) ESTG(6, z1.z, Z1.z) ESTG(7, z1.w, Z1.w)
#undef ESTG
    }
    __syncthreads();

    const int ni = (tx & 15) * 4;        // 16 n-groups of 4
    const int mi = (tx >> 4) * 2;        // 32 m-pairs

    // row-denominator pair for (mi, mi+1): this thread staged row ml=tx>>3
    // = mi + hib; partner lane tx^8 staged the sibling row.
    const float oden = __shfl_xor(rden, 8);
    const int hib = (tx >> 3) & 1;
    const float rd0 = hib ? oden : rden;
    const float rd1 = hib ? rden : oden;

    float p[2][4];
    #pragma unroll
    for (int i = 0; i < 2; ++i)
        #pragma unroll
        for (int j = 0; j < 4; ++j) p[i][j] = 1.0f;

    #pragma unroll 1                     // keep code size ~1 chunk (I$-friendly)
    for (int c = 0; c < 8; ++c) {
        #pragma unroll
        for (int k = 0; k < 8; ++k) {
            const int d = c * 8 + k;
            const float4 mf  = *reinterpret_cast<const float4*>(&sMen[d][mi]);  // Em0,Im0,Em1,Im1
            const float4 Ee4 = *reinterpret_cast<const float4*>(&sEe[d][ni]);
            const float4 Ie4 = *reinterpret_cast<const float4*>(&sIe[d][ni]);
            FD(p[0][0], mf.x, mf.y, Ee4.x, Ie4.x)
            FD(p[0][1], mf.x, mf.y, Ee4.y, Ie4.y)
            FD(p[0][2], mf.x, mf.y, Ee4.z, Ie4.z)
            FD(p[0][3], mf.x, mf.y, Ee4.w, Ie4.w)
            FD(p[1][0], mf.z, mf.w, Ee4.x, Ie4.x)
            FD(p[1][1], mf.z, mf.w, Ee4.y, Ie4.y)
            FD(p[1][2], mf.z, mf.w, Ee4.z, Ie4.z)
            FD(p[1][3], mf.z, mf.w, Ee4.w, Ie4.w)
        }
    }

    #pragma unroll
    for (int j = 0; j < 4; ++j) { p[0][j] *= rd0; p[1][j] *= rd1; }

    // ---- store: 2 rows x float4 per thread ----
    #pragma unroll
    for (int i = 0; i < 2; ++i) {
        const int m = m0 + mi + i;
        if (m >= M) continue;
        const int n = n0 + ni;
        if (n + 4 <= N) {
            *reinterpret_cast<float4*>(&out[(size_t)m * N + n]) =
                make_float4(p[i][0], p[i][1], p[i][2], p[i][3]);
        } else {
            #pragma unroll
            for (int j = 0; j < 4; ++j)
                if (n + j < N) out[(size_t)m * N + n + j] = p[i][j];
        }
    }
}

extern "C" void kernel_launch(void* const* d_in, const int* in_sizes, int n_in,
                              void* d_out, int out_size, void* d_ws, size_t ws_size,
                              hipStream_t stream) {
    const float* men = (const float*)d_in[0];
    const float* en  = (const float*)d_in[1];
    float* out = (float*)d_out;
    const int M = in_sizes[0] / 128;   // 256
    const int N = in_sizes[1] / 128;   // 20000
    dim3 grid((N + BN - 1) / BN, (M + BM - 1) / BM);
    ivr_kernel<<<grid, dim3(512), 0, stream>>>(men, en, out, M, N);
}